// Round 9
// baseline (6246.212 us; speedup 1.0000x reference)
//
#include <hip/hip_runtime.h>
#include <math.h>

#define S_   256
#define B_   32
#define H_   512
#define E_   256
#define V_   10000
#define K_   3
#define T_   32
#define N1_  96
#define BOS_ 1
#define EOS_ 1
#define NEG_ (-1000000000.0f)
#define RT   4        // per-row top-RT kept for exact beam merge (RT > K suffices)
#define LG_MT 79      // ceil(10000/128) m-tiles in logits GEMM
#define GST  (N1_ * 4 * H_)   // gts part stride (floats)

// ---------------------------------------------------------------------------
// Generic fp32 tiled GEMM (prologue + gts): 64x64 tile, TK=16, 256 thr, 4x4
// thread tile, register-prefetch double buffering, split-K via blockIdx.z.
// ---------------------------------------------------------------------------
__global__ __launch_bounds__(256) void gemm_k(
    const float* __restrict__ A, const float* __restrict__ B1,
    const float* __restrict__ B2, int split,
    const float* __restrict__ bias1, const float* __restrict__ bias2,
    float* __restrict__ C, int N, int Kd, int M, int klen, size_t cstride)
{
  __shared__ float As[16][64];
  __shared__ float Bs[16][64];
  const int tid = threadIdx.x;
  const int m0 = blockIdx.x * 64;
  const int n0 = blockIdx.y * 64;
  const int kstart = blockIdx.z * klen;
  const int kend = kstart + klen;
  const int tm = tid & 15, tn = tid >> 4;
  const int la_n = tid & 63;
  const int la_k = (tid >> 6) * 4;
  const int lb_m = (tid & 15) * 4;
  const int lb_k = tid >> 4;

  const int an = (n0 + la_n < N) ? (n0 + la_n) : 0;   // clamp (store guarded)
  const float* Arow = A + (size_t)an * Kd;
  float* Cpart = C + (size_t)blockIdx.z * cstride;

  float4 a_reg, b_reg;
  a_reg = *(const float4*)(Arow + kstart + la_k);
  {
    int krow = kstart + lb_k;
    const float* Brow = (krow < split) ? (B1 + (size_t)krow * M)
                                       : (B2 + (size_t)(krow - split) * M);
    int m = m0 + lb_m;
    if (m + 3 < M) b_reg = *(const float4*)(Brow + m);
    else {
      b_reg.x = (m + 0 < M) ? Brow[m + 0] : 0.f;
      b_reg.y = (m + 1 < M) ? Brow[m + 1] : 0.f;
      b_reg.z = (m + 2 < M) ? Brow[m + 2] : 0.f;
      b_reg.w = (m + 3 < M) ? Brow[m + 3] : 0.f;
    }
  }

  float acc[4][4] = {};

  for (int k0 = kstart; k0 < kend; k0 += 16) {
    if (k0 > kstart) __syncthreads();
    As[la_k + 0][la_n] = a_reg.x; As[la_k + 1][la_n] = a_reg.y;
    As[la_k + 2][la_n] = a_reg.z; As[la_k + 3][la_n] = a_reg.w;
    *(float4*)&Bs[lb_k][lb_m] = b_reg;
    __syncthreads();
    if (k0 + 16 < kend) {
      a_reg = *(const float4*)(Arow + (k0 + 16) + la_k);
      int krow = k0 + 16 + lb_k;
      const float* Brow = (krow < split) ? (B1 + (size_t)krow * M)
                                         : (B2 + (size_t)(krow - split) * M);
      int m = m0 + lb_m;
      if (m + 3 < M) b_reg = *(const float4*)(Brow + m);
      else {
        b_reg.x = (m + 0 < M) ? Brow[m + 0] : 0.f;
        b_reg.y = (m + 1 < M) ? Brow[m + 1] : 0.f;
        b_reg.z = (m + 2 < M) ? Brow[m + 2] : 0.f;
        b_reg.w = (m + 3 < M) ? Brow[m + 3] : 0.f;
      }
    }
#pragma unroll
    for (int kk = 0; kk < 16; kk++) {
      float4 av = *(const float4*)&As[kk][tn * 4];
      float4 bv = *(const float4*)&Bs[kk][tm * 4];
      float a[4] = {av.x, av.y, av.z, av.w};
      float b[4] = {bv.x, bv.y, bv.z, bv.w};
#pragma unroll
      for (int i = 0; i < 4; i++)
#pragma unroll
        for (int j = 0; j < 4; j++) acc[i][j] += a[i] * b[j];
    }
  }

  const bool addBias = (blockIdx.z == 0);
#pragma unroll
  for (int i = 0; i < 4; i++) {
    int n = n0 + tn * 4 + i;
    if (n >= N) continue;
#pragma unroll
    for (int j = 0; j < 4; j++) {
      int m = m0 + tm * 4 + j;
      if (m >= M) continue;
      float v = acc[i][j];
      if (addBias && bias1) v += bias1[m];
      if (addBias && bias2) v += bias2[m];
      Cpart[(size_t)n * M + m] = v;
    }
  }
}

// ---- top-k helpers (jax tie-break: value desc, then smaller index) ----
__device__ __forceinline__ bool tk_better(float va, int ia, float vb, int ib) {
  return (va > vb) || (va == vb && ia < ib);
}
__device__ __forceinline__ void tk_insertN(float v, int i, float* vv, int* ii) {
  if (!tk_better(v, i, vv[RT - 1], ii[RT - 1])) return;
  vv[RT - 1] = v; ii[RT - 1] = i;
#pragma unroll
  for (int q = RT - 1; q > 0; q--) {
    if (tk_better(vv[q], ii[q], vv[q - 1], ii[q - 1])) {
      float tv = vv[q]; vv[q] = vv[q - 1]; vv[q - 1] = tv;
      int ti = ii[q]; ii[q] = ii[q - 1]; ii[q - 1] = ti;
    }
  }
}
// merge sorted list (bv2,bi2) into (av,ai), keep RT best
__device__ __forceinline__ void tk_merge_reg(float* av, int* ai,
                                             const float* bv2, const int* bi2) {
  float rv[RT]; int ri[RT];
  int p = 0, q = 0;
#pragma unroll
  for (int t = 0; t < RT; t++) {
    bool ta;
    if (p >= RT) ta = false;
    else if (q >= RT) ta = true;
    else ta = tk_better(av[p], ai[p], bv2[q], bi2[q]);
    if (ta) { rv[t] = av[p]; ri[t] = ai[p]; p++; }
    else    { rv[t] = bv2[q]; ri[t] = bi2[q]; q++; }
  }
#pragma unroll
  for (int t = 0; t < RT; t++) { av[t] = rv[t]; ai[t] = ri[t]; }
}
// LDS pairwise merge (used by lgmerge_k)
__device__ __forceinline__ void tk_merge_lds(float* sv, int* si, int a, int b) {
  float rv[RT]; int ri[RT];
  int p = 0, q = 0;
#pragma unroll
  for (int t = 0; t < RT; t++) {
    bool ta;
    if (p >= RT) ta = false;
    else if (q >= RT) ta = true;
    else ta = tk_better(sv[a + p], si[a + p], sv[b + q], si[b + q]);
    if (ta) { rv[t] = sv[a + p]; ri[t] = si[a + p]; p++; }
    else    { rv[t] = sv[b + q]; ri[t] = si[b + q]; q++; }
  }
#pragma unroll
  for (int t = 0; t < RT; t++) { sv[a + t] = rv[t]; si[a + t] = ri[t]; }
}

// ---------------------------------------------------------------------------
// Logits GEMM, producer-consumer with 3-deep register-staged pipeline.
// 512 threads: waves 0-3 compute (VERBATIM baseline FMA chains over the
// identical kk order 0..1279 + fused top-RT epilogue), waves 4-7 loaders.
// BK=32: 40 barrier rounds. Loader uses TWO ping-pong register sets: during
// step it, ds_write chunk it+1 (loaded TWO iterations ago -> ~2100 cycles of
// latency cover) and issue global loads for chunk it+3.
// Grid: t=0 -> 79 blocks direct; t>0 -> 240 blocks XCD-grouped (round-7).
// ---------------------------------------------------------------------------
__global__ __launch_bounds__(512) void lggemm_k(
    const float* __restrict__ A, const float* __restrict__ Wc,
    const float* __restrict__ bc, int Nrows,
    float* __restrict__ ptv, int* __restrict__ pti,
    float* __restrict__ pmx, float* __restrict__ psm, int nt32)
{
  __shared__ float As[2][32][32];
  __shared__ float Bs[2][32][128];
  const int bid = blockIdx.x;
  int mt, nb2;
  if (nt32 == 1) {                 // t=0: 79 jobs, direct map
    if (bid >= LG_MT) return;
    mt = bid; nb2 = 0;
  } else {                         // t>0: XCD-grouped map (x = bid%8 = XCD)
    const int x = bid & 7, l = bid >> 3;
    if (l >= 30) return;           // uniform per block
    mt = x * 10 + l / 3;
    if (mt >= LG_MT) return;       // uniform per block (x=7, l>=27)
    nb2 = l % 3;
  }
  const int tid = threadIdx.x;
  const int m0 = mt * 128;
  const int n0 = nb2 * 32;
  const bool edge = (m0 + 128 > V_);

  if (tid < 256) {
    // -------- compute role: arithmetic verbatim from verified baseline -----
    const int tm = tid & 31;
    const int tn = tid >> 5;
    float acc[4][4] = {};

    for (int it = 0; it < 40; it++) {
      __syncthreads();                       // buf[it&1] ready
      const int cur = it & 1;
#pragma unroll
      for (int kk = 0; kk < 32; kk++) {
        float4 av = *(const float4*)&As[cur][kk][tn * 4];
        float4 bv = *(const float4*)&Bs[cur][kk][tm * 4];
        float a[4] = {av.x, av.y, av.z, av.w};
        float b[4] = {bv.x, bv.y, bv.z, bv.w};
#pragma unroll
        for (int i = 0; i < 4; i++)
#pragma unroll
          for (int j = 0; j < 4; j++) acc[i][j] += a[i] * b[j];
      }
    }

    // ---- fused epilogue: per-row (of this 128-col tile) top-RT, max, expsum
#pragma unroll
    for (int i = 0; i < 4; i++) {
      float vv[RT]; int ii[RT];
#pragma unroll
      for (int q = 0; q < RT; q++) { vv[q] = -3.4e38f; ii[q] = 0x7fffffff; }
      float vals[4];
#pragma unroll
      for (int j = 0; j < 4; j++) {
        int m = m0 + tm * 4 + j;
        float v = (m < V_) ? (acc[i][j] + bc[m]) : -3.4e38f;
        vals[j] = v;
        if (m < V_) tk_insertN(v, m, vv, ii);
      }
      // merge across the 32-lane half-wave (lanes share tn)
#pragma unroll
      for (int off = 1; off < 32; off <<= 1) {
        float ov[RT]; int oi[RT];
#pragma unroll
        for (int q = 0; q < RT; q++) {
          ov[q] = __shfl_xor(vv[q], off);
          oi[q] = __shfl_xor(ii[q], off);
        }
        tk_merge_reg(vv, ii, ov, oi);
      }
      const float rowmax = vv[0];
      float s = 0.f;
#pragma unroll
      for (int j = 0; j < 4; j++) {
        int m = m0 + tm * 4 + j;
        if (m < V_) s += expf(vals[j] - rowmax);
      }
#pragma unroll
      for (int off = 1; off < 32; off <<= 1) s += __shfl_xor(s, off);
      const int gr = n0 + tn * 4 + i;
      if (tm == 0 && gr < Nrows) {
        const size_t pb = (size_t)gr * LG_MT + mt;
#pragma unroll
        for (int q = 0; q < RT; q++) {
          ptv[pb * RT + q] = vv[q]; pti[pb * RT + q] = ii[q];
        }
        pmx[pb] = rowmax;
        psm[pb] = s;
      }
    }
  } else {
    // -------- loader role: 3-deep reg-staged pipeline (2 ping-pong sets) ---
    const int t2 = tid - 256;              // 0..255
    const int ar = t2 & 31;                // A row within 32
    const int ak = (t2 >> 5) * 4;          // A k-offset: 0,4,...,28
    const int arow_idx = (n0 + ar < Nrows) ? (n0 + ar) : 0;
    const float* Arow = A + (size_t)arow_idx * 1280;

    float4 a_reg[2];
    float4 b_reg[2][4];

    // issue global loads for 32-K chunk p into register set s
    auto issue = [&](int p, int s) {
      const int kb = p * 32;
      a_reg[s] = *(const float4*)(Arow + kb + ak);
#pragma unroll
      for (int l = 0; l < 4; l++) {
        const int idx = l * 256 + t2;
        const int kr = idx >> 5, c4 = (idx & 31) * 4;
        const float* Brow = Wc + (size_t)(kb + kr) * V_;
        if (!edge) b_reg[s][l] = *(const float4*)(Brow + m0 + c4);
        else {
          float4 bv;
          bv.x = (m0 + c4 + 0 < V_) ? Brow[m0 + c4 + 0] : 0.f;
          bv.y = (m0 + c4 + 1 < V_) ? Brow[m0 + c4 + 1] : 0.f;
          bv.z = (m0 + c4 + 2 < V_) ? Brow[m0 + c4 + 2] : 0.f;
          bv.w = (m0 + c4 + 3 < V_) ? Brow[m0 + c4 + 3] : 0.f;
          b_reg[s][l] = bv;
        }
      }
    };
    // write register set s into LDS buffer buf
    auto wr = [&](int buf, int s) {
      As[buf][ak + 0][ar] = a_reg[s].x; As[buf][ak + 1][ar] = a_reg[s].y;
      As[buf][ak + 2][ar] = a_reg[s].z; As[buf][ak + 3][ar] = a_reg[s].w;
#pragma unroll
      for (int l = 0; l < 4; l++) {
        const int idx = l * 256 + t2;
        const int kr = idx >> 5, c4 = (idx & 31) * 4;
        *(float4*)&Bs[buf][kr][c4] = b_reg[s][l];
      }
    };

    // prologue: chunk0 -> buf0; chunk1 -> set1; chunk2 -> set0 (in flight)
    issue(0, 0);
    wr(0, 0);                              // waits chunk0 loads (auto waitcnt)
    issue(1, 1);
    issue(2, 0);
    for (int it = 0; it < 40; it++) {
      __syncthreads();                     // compute starts on buf[it&1]
      if (it + 1 < 40) {
        const int s = (it + 1) & 1;
        wr((it + 1) & 1, s);               // chunk it+1 (issued 2 iters ago)
        if (it + 3 < 40) issue(it + 3, s); // set s freed -> launch it+3
      }
    }
  }
}

// Merge LG_MT per-tile partials per row -> rtv/rti/rmax/rlse. grid Nrows, 128 thr.
__global__ __launch_bounds__(128) void lgmerge_k(
    const float* __restrict__ ptv, const int* __restrict__ pti,
    const float* __restrict__ pmx, const float* __restrict__ psm,
    float* __restrict__ rtv, int* __restrict__ rti,
    float* __restrict__ rmax, float* __restrict__ rlse)
{
  __shared__ float sv[128 * RT];
  __shared__ int si[128 * RT];
  __shared__ float red[128];
  const int n = blockIdx.x, tid = threadIdx.x;
  float mx_t = -3.4e38f, sm_t = 0.f;
  float vv[RT]; int ii[RT];
#pragma unroll
  for (int q = 0; q < RT; q++) { vv[q] = -3.4e38f; ii[q] = 0x7fffffff; }
  if (tid < LG_MT) {
    const size_t pb = (size_t)n * LG_MT + tid;
#pragma unroll
    for (int q = 0; q < RT; q++) { vv[q] = ptv[pb * RT + q]; ii[q] = pti[pb * RT + q]; }
    mx_t = pmx[pb]; sm_t = psm[pb];
  }
#pragma unroll
  for (int q = 0; q < RT; q++) { sv[tid * RT + q] = vv[q]; si[tid * RT + q] = ii[q]; }
  __syncthreads();
  for (int st = 64; st; st >>= 1) {
    if (tid < st) tk_merge_lds(sv, si, tid * RT, (tid + st) * RT);
    __syncthreads();
  }
  red[tid] = mx_t; __syncthreads();
  for (int st = 64; st; st >>= 1) {
    if (tid < st) red[tid] = fmaxf(red[tid], red[tid + st]);
    __syncthreads();
  }
  const float Mg = red[0]; __syncthreads();
  red[tid] = sm_t * expf(mx_t - Mg); __syncthreads();
  for (int st = 64; st; st >>= 1) {
    if (tid < st) red[tid] += red[tid + st];
    __syncthreads();
  }
  if (tid < RT) { rtv[n * RT + tid] = sv[tid]; rti[n * RT + tid] = si[tid]; }
  if (tid == 0) { rmax[n] = Mg; rlse[n] = logf(red[0]); }
}

// ---------------------------------------------------------------------------
// pp[n][m0..m0+63] = sum_k h[n][k] * Wp[k][m].  grid (8, N), 256 thr.
// ---------------------------------------------------------------------------
__global__ __launch_bounds__(256) void ppgemv_k(
    const float* __restrict__ h, const float* __restrict__ Wp,
    float* __restrict__ pp)
{
  __shared__ float hS[512];
  __shared__ float red[256];
  const int n = blockIdx.y, tid = threadIdx.x;
  const int m = blockIdx.x * 64 + (tid & 63);
  const int kg = tid >> 6;
  hS[tid] = h[(size_t)n * H_ + tid];
  hS[256 + tid] = h[(size_t)n * H_ + 256 + tid];
  __syncthreads();
  float acc = 0.f;
#pragma unroll 4
  for (int k = kg * 128; k < kg * 128 + 128; k++)
    acc += hS[k] * Wp[(size_t)k * H_ + m];
  red[tid] = acc;
  __syncthreads();
  if (tid < 64) {
    float v = red[tid] + red[64 + tid] + red[128 + tid] + red[192 + tid];
    pp[(size_t)n * H_ + blockIdx.x * 64 + tid] = v;
  }
}

// ---------------------------------------------------------------------------
// Raw masked scores; stile 0 also fills xcat[ex | .. | hprev].
// grid (8 s-tiles, N), 512 thr.
// ---------------------------------------------------------------------------
__global__ __launch_bounds__(512) void score_k(
    const float* __restrict__ pp, const float* __restrict__ encp,
    const float* __restrict__ Wv, const float* __restrict__ mask,
    const float* __restrict__ emb, const int* __restrict__ tok,
    const float* __restrict__ h, float* __restrict__ sc,
    float* __restrict__ xcat, int bdiv, int tok_is_bos)
{
  __shared__ float ppS[512];
  __shared__ float WvS[512];
  const int n = blockIdx.y, tid = threadIdx.x;
  const int b = n / bdiv;
  ppS[tid] = pp[(size_t)n * H_ + tid];
  WvS[tid] = Wv[tid];
  if (blockIdx.x == 0) {
    xcat[(size_t)n * 1280 + E_ + H_ + tid] = h[(size_t)n * H_ + tid];  // hprev
    if (tid < E_) {
      int tk = tok_is_bos ? BOS_ : tok[n];
      xcat[(size_t)n * 1280 + tid] = emb[(size_t)tk * E_ + tid];       // ex
    }
  }
  __syncthreads();
  const int w = tid >> 6, lane = tid & 63;
#pragma unroll
  for (int j = 0; j < 4; j++) {
    int s = blockIdx.x * 32 + w * 4 + j;
    const float* ep = encp + ((size_t)s * B_ + b) * H_;
    float acc = 0.f;
#pragma unroll
    for (int r = 0; r < 8; r++) {
      int hh = r * 64 + lane;
      acc += tanhf(ppS[hh] + ep[hh]) * WvS[hh];
    }
#pragma unroll
    for (int off = 32; off; off >>= 1) acc += __shfl_xor(acc, off);
    if (lane == 0)
      sc[(size_t)n * S_ + s] = (mask[(size_t)b * S_ + s] == 0.f) ? NEG_ : acc;
  }
}

// ---------------------------------------------------------------------------
// ctx slice with in-block softmax recompute. grid (8 h-tiles, N), 256 thr.
// ---------------------------------------------------------------------------
__global__ __launch_bounds__(256) void ctx_k(
    const float* __restrict__ sc, const float* __restrict__ enc,
    float* __restrict__ xcat, int bdiv)
{
  __shared__ float aS[256];
  __shared__ float red[256];
  const int n = blockIdx.y, tid = threadIdx.x;
  const int b = n / bdiv;
  const int h0 = blockIdx.x * 64;
  float v = sc[(size_t)n * S_ + tid];
  red[tid] = v; __syncthreads();
  for (int st = 128; st; st >>= 1) {
    if (tid < st) red[tid] = fmaxf(red[tid], red[tid + st]);
    __syncthreads();
  }
  const float mx = red[0]; __syncthreads();
  float e = expf(v - mx);
  aS[tid] = e;
  red[tid] = e; __syncthreads();
  for (int st = 128; st; st >>= 1) {
    if (tid < st) red[tid] += red[tid + st];
    __syncthreads();
  }
  const float rsum = 1.f / red[0];
  __syncthreads();
  const int sgrp = tid >> 6, col = tid & 63;
  float acc = 0.f;
#pragma unroll 4
  for (int s0 = 0; s0 < S_; s0 += 4) {
    int s = s0 + sgrp;
    acc += aS[s] * enc[((size_t)s * B_ + b) * H_ + h0 + col];
  }
  red[tid] = acc; __syncthreads();
  if (tid < 64) {
    float total = red[tid] + red[64 + tid] + red[128 + tid] + red[192 + tid];
    xcat[(size_t)n * 1280 + E_ + h0 + tid] = total * rsum;
  }
}

__device__ __forceinline__ float sigf(float x) { return 1.f / (1.f + expf(-x)); }

// LSTM pointwise; sums 4 split-K gts parts; xcat in place: [ex|ctx|hprev]->[ex|h2|ctx].
__global__ __launch_bounds__(256) void lstm_k(
    const float* __restrict__ gts, const float* __restrict__ cprev,
    float* __restrict__ xcat, float* __restrict__ h2, float* __restrict__ c2)
{
  const int n = blockIdx.x, tid = threadIdx.x;
  float* xr = xcat + (size_t)n * 1280;
  for (int i = tid; i < H_; i += 256) {
    float gi = 0.f, gf = 0.f, gg = 0.f, go = 0.f;
#pragma unroll
    for (int p = 0; p < 4; p++) {
      const float* g = gts + (size_t)p * GST + (size_t)n * (4 * H_);
      gi += g[i]; gf += g[H_ + i]; gg += g[2 * H_ + i]; go += g[3 * H_ + i];
    }
    float ctx_i = xr[E_ + i];
    float cc = cprev[(size_t)n * H_ + i];
    float cv = sigf(gf) * cc + sigf(gi) * tanhf(gg);
    float hv = sigf(go) * tanhf(cv);
    c2[(size_t)n * H_ + i] = cv;
    h2[(size_t)n * H_ + i] = hv;
    xr[E_ + i] = hv;
    xr[E_ + H_ + i] = ctx_i;
  }
}

// step-0: beam expand + init. grid 96.
__global__ __launch_bounds__(256) void reorder0_k(
    const float* __restrict__ h2, const float* __restrict__ c2,
    float* __restrict__ h, float* __restrict__ c,
    const float* __restrict__ rtv, const int* __restrict__ rti,
    const float* __restrict__ rmax, const float* __restrict__ rlse,
    float* __restrict__ cum, int* __restrict__ eos, int* __restrict__ tok,
    int* __restrict__ preds)
{
  const int n = blockIdx.x, b = n / K_, r = n % K_, tid = threadIdx.x;
  for (int i = tid; i < H_; i += 256) {
    h[(size_t)n * H_ + i] = h2[(size_t)b * H_ + i];
    c[(size_t)n * H_ + i] = c2[(size_t)b * H_ + i];
  }
  if (tid < T_) preds[tid * N1_ + n] = 0;
  if (tid == 0) {
    float val = (rtv[b * RT + r] - rmax[b]) - rlse[b];
    int idx = rti[b * RT + r];
    preds[n] = idx;
    cum[n] = val; tok[n] = idx; eos[n] = (idx == EOS_) ? 1 : 0;
  }
}

// step-t: 12-candidate exact merge + gather. grid 96.
__global__ __launch_bounds__(256) void reorder1_k(
    const float* __restrict__ h2, const float* __restrict__ c2,
    float* __restrict__ h, float* __restrict__ c,
    const float* __restrict__ rtv, const int* __restrict__ rti,
    const float* __restrict__ rmax, const float* __restrict__ rlse,
    const float* __restrict__ cumOld, float* __restrict__ cumNew,
    const int* __restrict__ eosOld, int* __restrict__ eosNew,
    const int* __restrict__ pOld, int* __restrict__ pNew,
    int* __restrict__ tok, int t)
{
  __shared__ int s_g, s_tok;
  __shared__ float s_val;
  const int n = blockIdx.x, b = n / K_, r = n % K_, tid = threadIdx.x;
  if (tid == 0) {
    float cv[3 * RT]; int cj[3 * RT]; int cnt = 0;
    for (int k = 0; k < K_; k++) {
      int row = b * K_ + k;
      float ck = cumOld[row];
      if (eosOld[row]) {
        cv[cnt] = ck; cj[cnt] = k * V_ + EOS_; cnt++;
      } else {
        float mxk = rmax[row], lsk = rlse[row];
        for (int q = 0; q < RT; q++) {
          cv[cnt] = ck + ((rtv[row * RT + q] - mxk) - lsk);
          cj[cnt] = k * V_ + rti[row * RT + q]; cnt++;
        }
      }
    }
    int used = 0, pick = -1;
    for (int rep = 0; rep <= r; rep++) {
      pick = -1;
      for (int i2 = 0; i2 < cnt; i2++) {
        if ((used >> i2) & 1) continue;
        if (pick < 0 || tk_better(cv[i2], cj[i2], cv[pick], cj[pick])) pick = i2;
      }
      used |= 1 << pick;
    }
    int j = cj[pick];
    s_val = cv[pick];
    s_g = b * K_ + j / V_;
    s_tok = j % V_;
  }
  __syncthreads();
  const int g = s_g, ntok = s_tok;
  for (int i = tid; i < H_; i += 256) {
    h[(size_t)n * H_ + i] = h2[(size_t)g * H_ + i];
    c[(size_t)n * H_ + i] = c2[(size_t)g * H_ + i];
  }
  if (tid < T_) pNew[tid * N1_ + n] = (tid == t) ? ntok : pOld[tid * N1_ + g];
  if (tid == 0) {
    cumNew[n] = s_val;
    eosNew[n] = eosOld[g] | (ntok == EOS_ ? 1 : 0);
    tok[n] = ntok;
  }
}

__global__ __launch_bounds__(256) void finalout_k(
    const int* __restrict__ preds, const float* __restrict__ cum,
    float* __restrict__ out)
{
  const int i = blockIdx.x * 256 + threadIdx.x;
  if (i < T_ * B_) {
    int t = i >> 5, b = i & 31;
    out[i] = (float)preds[t * N1_ + b * K_];
  } else if (i < T_ * B_ + N1_) {
    out[i] = cum[i - T_ * B_];
  }
}

// ---------------------------------------------------------------------------
extern "C" void kernel_launch(void* const* d_in, const int* in_sizes, int n_in,
                              void* d_out, int out_size, void* d_ws, size_t ws_size,
                              hipStream_t stream)
{
  const float* enc    = (const float*)d_in[0];
  const float* last_h = (const float*)d_in[1];
  const float* last_c = (const float*)d_in[2];
  const float* mask   = (const float*)d_in[3];
  const float* emb    = (const float*)d_in[5];
  const float* Wp     = (const float*)d_in[6];
  const float* We     = (const float*)d_in[7];
  const float* Wv     = (const float*)d_in[8];
  const float* W_ih   = (const float*)d_in[9];
  const float* W_hh   = (const float*)d_in[10];
  const float* b_ih   = (const float*)d_in[11];
  const float* b_hh   = (const float*)d_in[12];
  const float* Wc     = (const float*)d_in[13];
  const float* bc     = (const float*)d_in[14];
  const float* W_init = (const float*)d_in[15];
  const float* b_init = (const float*)d_in[16];

  // ws carve — unconditional footprint ~21.8 MB (< proven 23.69 MB)
  float* w = (float*)d_ws;
  float* encp = w;  w += (size_t)S_ * B_ * H_;   // 16.78 MB
  float* h    = w;  w += N1_ * H_;
  float* c    = w;  w += N1_ * H_;
  float* h2   = w;  w += N1_ * H_;
  float* c2   = w;  w += N1_ * H_;
  float* pp   = w;  w += N1_ * H_;
  float* sc   = w;  w += N1_ * S_;
  float* xcat = w;  w += N1_ * 1280;             // doubles as x2 (in-place LSTM)
  float* gts  = w;  w += 4 * GST;                // 4 split-K parts
  float* ptv  = w;  w += (size_t)N1_ * LG_MT * RT;
  float* pmx  = w;  w += (size_t)N1_ * LG_MT;
  float* psm  = w;  w += (size_t)N1_ * LG_MT;
  float* rtv  = w;  w += N1_ * RT;
  float* rmax = w;  w += N1_;
  float* rlse = w;  w += N1_;
  float* cumA = w;  w += N1_;
  float* cumB = w;  w += N1_;
  int* pti  = (int*)w;  w += (size_t)N1_ * LG_MT * RT;
  int* rti  = (int*)w;  w += N1_ * RT;
  int* tok  = (int*)w;  w += N1_;
  int* eosA = (int*)w;  w += N1_;
  int* eosB = (int*)w;  w += N1_;
  int* pA   = (int*)w;  w += T_ * N1_;
  int* pB   = (int*)w;  w += T_ * N1_;

  // ---- prologue ----
  gemm_k<<<dim3(8, 1, 1), 256, 0, stream>>>(last_h + B_ * H_, W_init, nullptr, H_,
      b_init, nullptr, h, B_, H_, H_, H_, 0);
  gemm_k<<<dim3(8, 1, 1), 256, 0, stream>>>(last_c + B_ * H_, W_init, nullptr, H_,
      b_init, nullptr, c, B_, H_, H_, H_, 0);
  gemm_k<<<dim3(8, 128, 1), 256, 0, stream>>>(enc, We, nullptr, H_,
      nullptr, nullptr, encp, S_ * B_, H_, H_, H_, 0);

  for (int t = 0; t < T_; t++) {
    const int N = (t == 0) ? B_ : N1_;
    const int ntiles = (t == 0) ? 1 : 2;         // 64-row tiles for gts gemm
    const int nt32 = (t == 0) ? 1 : 3;           // 32-row tiles for logits gemm
    const int bdiv = (t == 0) ? 1 : K_;
    const int lgrid = (t == 0) ? LG_MT : 240;    // XCD-grouped 1-D grid at t>0

    ppgemv_k<<<dim3(8, N), 256, 0, stream>>>(h, Wp, pp);
    score_k<<<dim3(8, N), 512, 0, stream>>>(pp, encp, Wv, mask, emb, tok, h,
        sc, xcat, bdiv, t == 0 ? 1 : 0);
    ctx_k<<<dim3(8, N), 256, 0, stream>>>(sc, enc, xcat, bdiv);
    gemm_k<<<dim3(32, ntiles, 4), 256, 0, stream>>>(xcat, W_ih, W_hh, E_ + H_,
        b_ih, b_hh, gts, N, 1280, 4 * H_, 320, GST);
    lstm_k<<<N, 256, 0, stream>>>(gts, c, xcat, h2, c2);
    lggemm_k<<<lgrid, 512, 0, stream>>>(xcat, Wc, bc, N,
        ptv, pti, pmx, psm, nt32);
    lgmerge_k<<<N, 128, 0, stream>>>(ptv, pti, pmx, psm, rtv, rti, rmax, rlse);
    if (t == 0) {
      reorder0_k<<<N1_, 256, 0, stream>>>(h2, c2, h, c, rtv, rti, rmax, rlse,
          cumA, eosA, tok, pA);
    } else {
      float* cumOld = (t & 1) ? cumA : cumB;
      float* cumNew = (t & 1) ? cumB : cumA;
      int* eosOld = (t & 1) ? eosA : eosB;
      int* eosNew = (t & 1) ? eosB : eosA;
      int* pOld   = (t & 1) ? pA : pB;
      int* pNew   = (t & 1) ? pB : pA;
      reorder1_k<<<N1_, 256, 0, stream>>>(h2, c2, h, c, rtv, rti, rmax, rlse,
          cumOld, cumNew, eosOld, eosNew, pOld, pNew, tok, t);
    }
  }

  // t=31 odd -> preds in pB, cum in cumB
  finalout_k<<<5, 256, 0, stream>>>(pB, cumB, (float*)d_out);
}

// Round 10
// 4621.695 us; speedup vs baseline: 1.3515x; 1.3515x over previous
//
#include <hip/hip_runtime.h>
#include <math.h>

#define S_   256
#define B_   32
#define H_   512
#define E_   256
#define V_   10000
#define K_   3
#define T_   32
#define N1_  96
#define BOS_ 1
#define EOS_ 1
#define NEG_ (-1000000000.0f)
#define RT   4        // per-row top-RT kept for exact beam merge (RT > K suffices)
#define LG_MT 157     // ceil(10000/64) m-tiles in logits GEMM (64-col tiles)
#define GST  (N1_ * 4 * H_)   // gts part stride (floats)

// ---------------------------------------------------------------------------
// Generic fp32 tiled GEMM (prologue + gts): 64x64 tile, TK=16, 256 thr, 4x4
// thread tile, register-prefetch double buffering, split-K via blockIdx.z.
// ---------------------------------------------------------------------------
__global__ __launch_bounds__(256) void gemm_k(
    const float* __restrict__ A, const float* __restrict__ B1,
    const float* __restrict__ B2, int split,
    const float* __restrict__ bias1, const float* __restrict__ bias2,
    float* __restrict__ C, int N, int Kd, int M, int klen, size_t cstride)
{
  __shared__ float As[16][64];
  __shared__ float Bs[16][64];
  const int tid = threadIdx.x;
  const int m0 = blockIdx.x * 64;
  const int n0 = blockIdx.y * 64;
  const int kstart = blockIdx.z * klen;
  const int kend = kstart + klen;
  const int tm = tid & 15, tn = tid >> 4;
  const int la_n = tid & 63;
  const int la_k = (tid >> 6) * 4;
  const int lb_m = (tid & 15) * 4;
  const int lb_k = tid >> 4;

  const int an = (n0 + la_n < N) ? (n0 + la_n) : 0;   // clamp (store guarded)
  const float* Arow = A + (size_t)an * Kd;
  float* Cpart = C + (size_t)blockIdx.z * cstride;

  float4 a_reg, b_reg;
  a_reg = *(const float4*)(Arow + kstart + la_k);
  {
    int krow = kstart + lb_k;
    const float* Brow = (krow < split) ? (B1 + (size_t)krow * M)
                                       : (B2 + (size_t)(krow - split) * M);
    int m = m0 + lb_m;
    if (m + 3 < M) b_reg = *(const float4*)(Brow + m);
    else {
      b_reg.x = (m + 0 < M) ? Brow[m + 0] : 0.f;
      b_reg.y = (m + 1 < M) ? Brow[m + 1] : 0.f;
      b_reg.z = (m + 2 < M) ? Brow[m + 2] : 0.f;
      b_reg.w = (m + 3 < M) ? Brow[m + 3] : 0.f;
    }
  }

  float acc[4][4] = {};

  for (int k0 = kstart; k0 < kend; k0 += 16) {
    if (k0 > kstart) __syncthreads();
    As[la_k + 0][la_n] = a_reg.x; As[la_k + 1][la_n] = a_reg.y;
    As[la_k + 2][la_n] = a_reg.z; As[la_k + 3][la_n] = a_reg.w;
    *(float4*)&Bs[lb_k][lb_m] = b_reg;
    __syncthreads();
    if (k0 + 16 < kend) {
      a_reg = *(const float4*)(Arow + (k0 + 16) + la_k);
      int krow = k0 + 16 + lb_k;
      const float* Brow = (krow < split) ? (B1 + (size_t)krow * M)
                                         : (B2 + (size_t)(krow - split) * M);
      int m = m0 + lb_m;
      if (m + 3 < M) b_reg = *(const float4*)(Brow + m);
      else {
        b_reg.x = (m + 0 < M) ? Brow[m + 0] : 0.f;
        b_reg.y = (m + 1 < M) ? Brow[m + 1] : 0.f;
        b_reg.z = (m + 2 < M) ? Brow[m + 2] : 0.f;
        b_reg.w = (m + 3 < M) ? Brow[m + 3] : 0.f;
      }
    }
#pragma unroll
    for (int kk = 0; kk < 16; kk++) {
      float4 av = *(const float4*)&As[kk][tn * 4];
      float4 bv = *(const float4*)&Bs[kk][tm * 4];
      float a[4] = {av.x, av.y, av.z, av.w};
      float b[4] = {bv.x, bv.y, bv.z, bv.w};
#pragma unroll
      for (int i = 0; i < 4; i++)
#pragma unroll
        for (int j = 0; j < 4; j++) acc[i][j] += a[i] * b[j];
    }
  }

  const bool addBias = (blockIdx.z == 0);
#pragma unroll
  for (int i = 0; i < 4; i++) {
    int n = n0 + tn * 4 + i;
    if (n >= N) continue;
#pragma unroll
    for (int j = 0; j < 4; j++) {
      int m = m0 + tm * 4 + j;
      if (m >= M) continue;
      float v = acc[i][j];
      if (addBias && bias1) v += bias1[m];
      if (addBias && bias2) v += bias2[m];
      Cpart[(size_t)n * M + m] = v;
    }
  }
}

// ---- top-k helpers (jax tie-break: value desc, then smaller index) ----
__device__ __forceinline__ bool tk_better(float va, int ia, float vb, int ib) {
  return (va > vb) || (va == vb && ia < ib);
}
__device__ __forceinline__ void tk_insertN(float v, int i, float* vv, int* ii) {
  if (!tk_better(v, i, vv[RT - 1], ii[RT - 1])) return;
  vv[RT - 1] = v; ii[RT - 1] = i;
#pragma unroll
  for (int q = RT - 1; q > 0; q--) {
    if (tk_better(vv[q], ii[q], vv[q - 1], ii[q - 1])) {
      float tv = vv[q]; vv[q] = vv[q - 1]; vv[q - 1] = tv;
      int ti = ii[q]; ii[q] = ii[q - 1]; ii[q - 1] = ti;
    }
  }
}
// merge sorted list (bv2,bi2) into (av,ai), keep RT best
__device__ __forceinline__ void tk_merge_reg(float* av, int* ai,
                                             const float* bv2, const int* bi2) {
  float rv[RT]; int ri[RT];
  int p = 0, q = 0;
#pragma unroll
  for (int t = 0; t < RT; t++) {
    bool ta;
    if (p >= RT) ta = false;
    else if (q >= RT) ta = true;
    else ta = tk_better(av[p], ai[p], bv2[q], bi2[q]);
    if (ta) { rv[t] = av[p]; ri[t] = ai[p]; p++; }
    else    { rv[t] = bv2[q]; ri[t] = bi2[q]; q++; }
  }
#pragma unroll
  for (int t = 0; t < RT; t++) { av[t] = rv[t]; ai[t] = ri[t]; }
}
// LDS pairwise merge (used by lgmerge_k)
__device__ __forceinline__ void tk_merge_lds(float* sv, int* si, int a, int b) {
  float rv[RT]; int ri[RT];
  int p = 0, q = 0;
#pragma unroll
  for (int t = 0; t < RT; t++) {
    bool ta;
    if (p >= RT) ta = false;
    else if (q >= RT) ta = true;
    else ta = tk_better(sv[a + p], si[a + p], sv[b + q], si[b + q]);
    if (ta) { rv[t] = sv[a + p]; ri[t] = si[a + p]; p++; }
    else    { rv[t] = sv[b + q]; ri[t] = si[b + q]; q++; }
  }
#pragma unroll
  for (int t = 0; t < RT; t++) { sv[a + t] = rv[t]; si[a + t] = ri[t]; }
}

// ---------------------------------------------------------------------------
// Logits GEMM, producer-consumer, 64-col tiles for 2x grid parallelism.
// 512 threads: waves 0-3 compute (each output's FMA chain iterates the
// IDENTICAL kk order 0..1279 -> logits bit-identical to baseline), waves 4-7
// run the round-8 2-deep register-staged loader. Tile 32 rows x 64 cols,
// thread tile 4x2. Per-tile exact top-RT + rowmax + expsum epilogue.
// Grid: t=0 -> 157 blocks direct; t>0 -> 480 blocks XCD-grouped
// (x=bid&7 -> XCD; 3 n-jobs of one Wc m-tile share an XCD's L2).
// ---------------------------------------------------------------------------
__global__ __launch_bounds__(512) void lggemm_k(
    const float* __restrict__ A, const float* __restrict__ Wc,
    const float* __restrict__ bc, int Nrows,
    float* __restrict__ ptv, int* __restrict__ pti,
    float* __restrict__ pmx, float* __restrict__ psm, int nt32)
{
  __shared__ float As[2][32][32];
  __shared__ float Bs[2][32][64];
  const int bid = blockIdx.x;
  int mt, nb2;
  if (nt32 == 1) {                 // t=0: 157 jobs, direct map
    if (bid >= LG_MT) return;
    mt = bid; nb2 = 0;
  } else {                         // t>0: XCD-grouped map (x = bid%8 = XCD)
    const int x = bid & 7, l = bid >> 3;
    if (l >= 60) return;           // uniform per block
    mt = x * 20 + l / 3;
    if (mt >= LG_MT) return;       // uniform per block (x=7, l>=51)
    nb2 = l % 3;
  }
  const int tid = threadIdx.x;
  const int m0 = mt * 64;
  const int n0 = nb2 * 32;
  const bool edge = (m0 + 64 > V_);

  if (tid < 256) {
    // -------- compute role: 4x2 thread tile, kk order 0..1279 unchanged ----
    const int tm = tid & 31;       // col group (x2 cols)
    const int tn = tid >> 5;       // row group (x4 rows)
    float acc[4][2] = {};

    for (int it = 0; it < 40; it++) {
      __syncthreads();                       // buf[it&1] ready
      const int cur = it & 1;
#pragma unroll
      for (int kk = 0; kk < 32; kk++) {
        float4 av = *(const float4*)&As[cur][kk][tn * 4];
        float2 bv = *(const float2*)&Bs[cur][kk][tm * 2];
        float a[4] = {av.x, av.y, av.z, av.w};
        float b[2] = {bv.x, bv.y};
#pragma unroll
        for (int i = 0; i < 4; i++)
#pragma unroll
          for (int j = 0; j < 2; j++) acc[i][j] += a[i] * b[j];
      }
    }

    // ---- fused epilogue: per-row (of this 64-col tile) top-RT, max, expsum
#pragma unroll
    for (int i = 0; i < 4; i++) {
      float vv[RT]; int ii[RT];
#pragma unroll
      for (int q = 0; q < RT; q++) { vv[q] = -3.4e38f; ii[q] = 0x7fffffff; }
      float vals[2];
#pragma unroll
      for (int j = 0; j < 2; j++) {
        int m = m0 + tm * 2 + j;
        float v = (m < V_) ? (acc[i][j] + bc[m]) : -3.4e38f;
        vals[j] = v;
        if (m < V_) tk_insertN(v, m, vv, ii);
      }
      // merge across the 32-lane half-wave (lanes share tn)
#pragma unroll
      for (int off = 1; off < 32; off <<= 1) {
        float ov[RT]; int oi[RT];
#pragma unroll
        for (int q = 0; q < RT; q++) {
          ov[q] = __shfl_xor(vv[q], off);
          oi[q] = __shfl_xor(ii[q], off);
        }
        tk_merge_reg(vv, ii, ov, oi);
      }
      const float rowmax = vv[0];
      float s = 0.f;
#pragma unroll
      for (int j = 0; j < 2; j++) {
        int m = m0 + tm * 2 + j;
        if (m < V_) s += expf(vals[j] - rowmax);
      }
#pragma unroll
      for (int off = 1; off < 32; off <<= 1) s += __shfl_xor(s, off);
      const int gr = n0 + tn * 4 + i;
      if (tm == 0 && gr < Nrows) {
        const size_t pb = (size_t)gr * LG_MT + mt;
#pragma unroll
        for (int q = 0; q < RT; q++) {
          ptv[pb * RT + q] = vv[q]; pti[pb * RT + q] = ii[q];
        }
        pmx[pb] = rowmax;
        psm[pb] = s;
      }
    }
  } else {
    // -------- loader role: round-8 2-deep reg-staged pipeline --------------
    const int t2 = tid - 256;              // 0..255
    const int ar = t2 & 31;                // A row within 32
    const int ak = (t2 >> 5) * 4;          // A k-offset: 0,4,...,28
    const int arow_idx = (n0 + ar < Nrows) ? (n0 + ar) : 0;
    const float* Arow = A + (size_t)arow_idx * 1280;

    float4 a_reg;
    float4 b_reg[2];

    // issue global loads for 32-K chunk p into registers
    auto issue = [&](int p) {
      const int kb = p * 32;
      a_reg = *(const float4*)(Arow + kb + ak);
#pragma unroll
      for (int l = 0; l < 2; l++) {
        const int idx = l * 256 + t2;
        const int kr = idx >> 4, c4 = (idx & 15) * 4;
        const float* Brow = Wc + (size_t)(kb + kr) * V_;
        if (!edge) b_reg[l] = *(const float4*)(Brow + m0 + c4);
        else {
          float4 bv;
          bv.x = (m0 + c4 + 0 < V_) ? Brow[m0 + c4 + 0] : 0.f;
          bv.y = (m0 + c4 + 1 < V_) ? Brow[m0 + c4 + 1] : 0.f;
          bv.z = (m0 + c4 + 2 < V_) ? Brow[m0 + c4 + 2] : 0.f;
          bv.w = (m0 + c4 + 3 < V_) ? Brow[m0 + c4 + 3] : 0.f;
          b_reg[l] = bv;
        }
      }
    };
    // write staged registers into LDS buffer buf
    auto wr = [&](int buf) {
      As[buf][ak + 0][ar] = a_reg.x; As[buf][ak + 1][ar] = a_reg.y;
      As[buf][ak + 2][ar] = a_reg.z; As[buf][ak + 3][ar] = a_reg.w;
#pragma unroll
      for (int l = 0; l < 2; l++) {
        const int idx = l * 256 + t2;
        const int kr = idx >> 4, c4 = (idx & 15) * 4;
        *(float4*)&Bs[buf][kr][c4] = b_reg[l];
      }
    };

    issue(0);
    wr(0);                                 // chunk 0 -> buf 0 (waitcnt auto)
    issue(1);                              // chunk 1 in flight
    for (int it = 0; it < 40; it++) {
      __syncthreads();                     // compute starts on buf[it&1]
      if (it + 1 < 40) {
        wr((it + 1) & 1);                  // write chunk it+1 (loaded last step)
        if (it + 2 < 40) issue(it + 2);    // launch loads for chunk it+2
      }
    }
  }
}

// Merge LG_MT=157 per-tile partials per row -> rtv/rti/rmax/rlse.
// grid Nrows, 256 thr (slots 157..255 neutral).
__global__ __launch_bounds__(256) void lgmerge_k(
    const float* __restrict__ ptv, const int* __restrict__ pti,
    const float* __restrict__ pmx, const float* __restrict__ psm,
    float* __restrict__ rtv, int* __restrict__ rti,
    float* __restrict__ rmax, float* __restrict__ rlse)
{
  __shared__ float sv[256 * RT];
  __shared__ int si[256 * RT];
  __shared__ float red[256];
  const int n = blockIdx.x, tid = threadIdx.x;
  float mx_t = -3.4e38f, sm_t = 0.f;
  float vv[RT]; int ii[RT];
#pragma unroll
  for (int q = 0; q < RT; q++) { vv[q] = -3.4e38f; ii[q] = 0x7fffffff; }
  if (tid < LG_MT) {
    const size_t pb = (size_t)n * LG_MT + tid;
#pragma unroll
    for (int q = 0; q < RT; q++) { vv[q] = ptv[pb * RT + q]; ii[q] = pti[pb * RT + q]; }
    mx_t = pmx[pb]; sm_t = psm[pb];
  }
#pragma unroll
  for (int q = 0; q < RT; q++) { sv[tid * RT + q] = vv[q]; si[tid * RT + q] = ii[q]; }
  __syncthreads();
  for (int st = 128; st; st >>= 1) {
    if (tid < st) tk_merge_lds(sv, si, tid * RT, (tid + st) * RT);
    __syncthreads();
  }
  red[tid] = mx_t; __syncthreads();
  for (int st = 128; st; st >>= 1) {
    if (tid < st) red[tid] = fmaxf(red[tid], red[tid + st]);
    __syncthreads();
  }
  const float Mg = red[0]; __syncthreads();
  red[tid] = sm_t * expf(mx_t - Mg); __syncthreads();
  for (int st = 128; st; st >>= 1) {
    if (tid < st) red[tid] += red[tid + st];
    __syncthreads();
  }
  if (tid < RT) { rtv[n * RT + tid] = sv[tid]; rti[n * RT + tid] = si[tid]; }
  if (tid == 0) { rmax[n] = Mg; rlse[n] = logf(red[0]); }
}

// ---------------------------------------------------------------------------
// pp[n][m0..m0+63] = sum_k h[n][k] * Wp[k][m].  grid (8, N), 256 thr.
// ---------------------------------------------------------------------------
__global__ __launch_bounds__(256) void ppgemv_k(
    const float* __restrict__ h, const float* __restrict__ Wp,
    float* __restrict__ pp)
{
  __shared__ float hS[512];
  __shared__ float red[256];
  const int n = blockIdx.y, tid = threadIdx.x;
  const int m = blockIdx.x * 64 + (tid & 63);
  const int kg = tid >> 6;
  hS[tid] = h[(size_t)n * H_ + tid];
  hS[256 + tid] = h[(size_t)n * H_ + 256 + tid];
  __syncthreads();
  float acc = 0.f;
#pragma unroll 4
  for (int k = kg * 128; k < kg * 128 + 128; k++)
    acc += hS[k] * Wp[(size_t)k * H_ + m];
  red[tid] = acc;
  __syncthreads();
  if (tid < 64) {
    float v = red[tid] + red[64 + tid] + red[128 + tid] + red[192 + tid];
    pp[(size_t)n * H_ + blockIdx.x * 64 + tid] = v;
  }
}

// ---------------------------------------------------------------------------
// Raw masked scores; stile 0 also fills xcat[ex | .. | hprev].
// grid (8 s-tiles, N), 512 thr.
// ---------------------------------------------------------------------------
__global__ __launch_bounds__(512) void score_k(
    const float* __restrict__ pp, const float* __restrict__ encp,
    const float* __restrict__ Wv, const float* __restrict__ mask,
    const float* __restrict__ emb, const int* __restrict__ tok,
    const float* __restrict__ h, float* __restrict__ sc,
    float* __restrict__ xcat, int bdiv, int tok_is_bos)
{
  __shared__ float ppS[512];
  __shared__ float WvS[512];
  const int n = blockIdx.y, tid = threadIdx.x;
  const int b = n / bdiv;
  ppS[tid] = pp[(size_t)n * H_ + tid];
  WvS[tid] = Wv[tid];
  if (blockIdx.x == 0) {
    xcat[(size_t)n * 1280 + E_ + H_ + tid] = h[(size_t)n * H_ + tid];  // hprev
    if (tid < E_) {
      int tk = tok_is_bos ? BOS_ : tok[n];
      xcat[(size_t)n * 1280 + tid] = emb[(size_t)tk * E_ + tid];       // ex
    }
  }
  __syncthreads();
  const int w = tid >> 6, lane = tid & 63;
#pragma unroll
  for (int j = 0; j < 4; j++) {
    int s = blockIdx.x * 32 + w * 4 + j;
    const float* ep = encp + ((size_t)s * B_ + b) * H_;
    float acc = 0.f;
#pragma unroll
    for (int r = 0; r < 8; r++) {
      int hh = r * 64 + lane;
      acc += tanhf(ppS[hh] + ep[hh]) * WvS[hh];
    }
#pragma unroll
    for (int off = 32; off; off >>= 1) acc += __shfl_xor(acc, off);
    if (lane == 0)
      sc[(size_t)n * S_ + s] = (mask[(size_t)b * S_ + s] == 0.f) ? NEG_ : acc;
  }
}

// ---------------------------------------------------------------------------
// ctx slice with in-block softmax recompute. grid (8 h-tiles, N), 256 thr.
// ---------------------------------------------------------------------------
__global__ __launch_bounds__(256) void ctx_k(
    const float* __restrict__ sc, const float* __restrict__ enc,
    float* __restrict__ xcat, int bdiv)
{
  __shared__ float aS[256];
  __shared__ float red[256];
  const int n = blockIdx.y, tid = threadIdx.x;
  const int b = n / bdiv;
  const int h0 = blockIdx.x * 64;
  float v = sc[(size_t)n * S_ + tid];
  red[tid] = v; __syncthreads();
  for (int st = 128; st; st >>= 1) {
    if (tid < st) red[tid] = fmaxf(red[tid], red[tid + st]);
    __syncthreads();
  }
  const float mx = red[0]; __syncthreads();
  float e = expf(v - mx);
  aS[tid] = e;
  red[tid] = e; __syncthreads();
  for (int st = 128; st; st >>= 1) {
    if (tid < st) red[tid] += red[tid + st];
    __syncthreads();
  }
  const float rsum = 1.f / red[0];
  __syncthreads();
  const int sgrp = tid >> 6, col = tid & 63;
  float acc = 0.f;
#pragma unroll 4
  for (int s0 = 0; s0 < S_; s0 += 4) {
    int s = s0 + sgrp;
    acc += aS[s] * enc[((size_t)s * B_ + b) * H_ + h0 + col];
  }
  red[tid] = acc; __syncthreads();
  if (tid < 64) {
    float total = red[tid] + red[64 + tid] + red[128 + tid] + red[192 + tid];
    xcat[(size_t)n * 1280 + E_ + h0 + tid] = total * rsum;
  }
}

__device__ __forceinline__ float sigf(float x) { return 1.f / (1.f + expf(-x)); }

// LSTM pointwise; sums 4 split-K gts parts; xcat in place: [ex|ctx|hprev]->[ex|h2|ctx].
__global__ __launch_bounds__(256) void lstm_k(
    const float* __restrict__ gts, const float* __restrict__ cprev,
    float* __restrict__ xcat, float* __restrict__ h2, float* __restrict__ c2)
{
  const int n = blockIdx.x, tid = threadIdx.x;
  float* xr = xcat + (size_t)n * 1280;
  for (int i = tid; i < H_; i += 256) {
    float gi = 0.f, gf = 0.f, gg = 0.f, go = 0.f;
#pragma unroll
    for (int p = 0; p < 4; p++) {
      const float* g = gts + (size_t)p * GST + (size_t)n * (4 * H_);
      gi += g[i]; gf += g[H_ + i]; gg += g[2 * H_ + i]; go += g[3 * H_ + i];
    }
    float ctx_i = xr[E_ + i];
    float cc = cprev[(size_t)n * H_ + i];
    float cv = sigf(gf) * cc + sigf(gi) * tanhf(gg);
    float hv = sigf(go) * tanhf(cv);
    c2[(size_t)n * H_ + i] = cv;
    h2[(size_t)n * H_ + i] = hv;
    xr[E_ + i] = hv;
    xr[E_ + H_ + i] = ctx_i;
  }
}

// step-0: beam expand + init. grid 96.
__global__ __launch_bounds__(256) void reorder0_k(
    const float* __restrict__ h2, const float* __restrict__ c2,
    float* __restrict__ h, float* __restrict__ c,
    const float* __restrict__ rtv, const int* __restrict__ rti,
    const float* __restrict__ rmax, const float* __restrict__ rlse,
    float* __restrict__ cum, int* __restrict__ eos, int* __restrict__ tok,
    int* __restrict__ preds)
{
  const int n = blockIdx.x, b = n / K_, r = n % K_, tid = threadIdx.x;
  for (int i = tid; i < H_; i += 256) {
    h[(size_t)n * H_ + i] = h2[(size_t)b * H_ + i];
    c[(size_t)n * H_ + i] = c2[(size_t)b * H_ + i];
  }
  if (tid < T_) preds[tid * N1_ + n] = 0;
  if (tid == 0) {
    float val = (rtv[b * RT + r] - rmax[b]) - rlse[b];
    int idx = rti[b * RT + r];
    preds[n] = idx;
    cum[n] = val; tok[n] = idx; eos[n] = (idx == EOS_) ? 1 : 0;
  }
}

// step-t: 12-candidate exact merge + gather. grid 96.
__global__ __launch_bounds__(256) void reorder1_k(
    const float* __restrict__ h2, const float* __restrict__ c2,
    float* __restrict__ h, float* __restrict__ c,
    const float* __restrict__ rtv, const int* __restrict__ rti,
    const float* __restrict__ rmax, const float* __restrict__ rlse,
    const float* __restrict__ cumOld, float* __restrict__ cumNew,
    const int* __restrict__ eosOld, int* __restrict__ eosNew,
    const int* __restrict__ pOld, int* __restrict__ pNew,
    int* __restrict__ tok, int t)
{
  __shared__ int s_g, s_tok;
  __shared__ float s_val;
  const int n = blockIdx.x, b = n / K_, r = n % K_, tid = threadIdx.x;
  if (tid == 0) {
    float cv[3 * RT]; int cj[3 * RT]; int cnt = 0;
    for (int k = 0; k < K_; k++) {
      int row = b * K_ + k;
      float ck = cumOld[row];
      if (eosOld[row]) {
        cv[cnt] = ck; cj[cnt] = k * V_ + EOS_; cnt++;
      } else {
        float mxk = rmax[row], lsk = rlse[row];
        for (int q = 0; q < RT; q++) {
          cv[cnt] = ck + ((rtv[row * RT + q] - mxk) - lsk);
          cj[cnt] = k * V_ + rti[row * RT + q]; cnt++;
        }
      }
    }
    int used = 0, pick = -1;
    for (int rep = 0; rep <= r; rep++) {
      pick = -1;
      for (int i2 = 0; i2 < cnt; i2++) {
        if ((used >> i2) & 1) continue;
        if (pick < 0 || tk_better(cv[i2], cj[i2], cv[pick], cj[pick])) pick = i2;
      }
      used |= 1 << pick;
    }
    int j = cj[pick];
    s_val = cv[pick];
    s_g = b * K_ + j / V_;
    s_tok = j % V_;
  }
  __syncthreads();
  const int g = s_g, ntok = s_tok;
  for (int i = tid; i < H_; i += 256) {
    h[(size_t)n * H_ + i] = h2[(size_t)g * H_ + i];
    c[(size_t)n * H_ + i] = c2[(size_t)g * H_ + i];
  }
  if (tid < T_) pNew[tid * N1_ + n] = (tid == t) ? ntok : pOld[tid * N1_ + g];
  if (tid == 0) {
    cumNew[n] = s_val;
    eosNew[n] = eosOld[g] | (ntok == EOS_ ? 1 : 0);
    tok[n] = ntok;
  }
}

__global__ __launch_bounds__(256) void finalout_k(
    const int* __restrict__ preds, const float* __restrict__ cum,
    float* __restrict__ out)
{
  const int i = blockIdx.x * 256 + threadIdx.x;
  if (i < T_ * B_) {
    int t = i >> 5, b = i & 31;
    out[i] = (float)preds[t * N1_ + b * K_];
  } else if (i < T_ * B_ + N1_) {
    out[i] = cum[i - T_ * B_];
  }
}

// ---------------------------------------------------------------------------
extern "C" void kernel_launch(void* const* d_in, const int* in_sizes, int n_in,
                              void* d_out, int out_size, void* d_ws, size_t ws_size,
                              hipStream_t stream)
{
  const float* enc    = (const float*)d_in[0];
  const float* last_h = (const float*)d_in[1];
  const float* last_c = (const float*)d_in[2];
  const float* mask   = (const float*)d_in[3];
  const float* emb    = (const float*)d_in[5];
  const float* Wp     = (const float*)d_in[6];
  const float* We     = (const float*)d_in[7];
  const float* Wv     = (const float*)d_in[8];
  const float* W_ih   = (const float*)d_in[9];
  const float* W_hh   = (const float*)d_in[10];
  const float* b_ih   = (const float*)d_in[11];
  const float* b_hh   = (const float*)d_in[12];
  const float* Wc     = (const float*)d_in[13];
  const float* bc     = (const float*)d_in[14];
  const float* W_init = (const float*)d_in[15];
  const float* b_init = (const float*)d_in[16];

  // ws carve — ~22.1 MB (< proven 23.69 MB)
  float* w = (float*)d_ws;
  float* encp = w;  w += (size_t)S_ * B_ * H_;   // 16.78 MB
  float* h    = w;  w += N1_ * H_;
  float* c    = w;  w += N1_ * H_;
  float* h2   = w;  w += N1_ * H_;
  float* c2   = w;  w += N1_ * H_;
  float* pp   = w;  w += N1_ * H_;
  float* sc   = w;  w += N1_ * S_;
  float* xcat = w;  w += N1_ * 1280;             // doubles as x2 (in-place LSTM)
  float* gts  = w;  w += 4 * GST;                // 4 split-K parts
  float* ptv  = w;  w += (size_t)N1_ * LG_MT * RT;
  float* pmx  = w;  w += (size_t)N1_ * LG_MT;
  float* psm  = w;  w += (size_t)N1_ * LG_MT;
  float* rtv  = w;  w += N1_ * RT;
  float* rmax = w;  w += N1_;
  float* rlse = w;  w += N1_;
  float* cumA = w;  w += N1_;
  float* cumB = w;  w += N1_;
  int* pti  = (int*)w;  w += (size_t)N1_ * LG_MT * RT;
  int* rti  = (int*)w;  w += N1_ * RT;
  int* tok  = (int*)w;  w += N1_;
  int* eosA = (int*)w;  w += N1_;
  int* eosB = (int*)w;  w += N1_;
  int* pA   = (int*)w;  w += T_ * N1_;
  int* pB   = (int*)w;  w += T_ * N1_;

  // ---- prologue ----
  gemm_k<<<dim3(8, 1, 1), 256, 0, stream>>>(last_h + B_ * H_, W_init, nullptr, H_,
      b_init, nullptr, h, B_, H_, H_, H_, 0);
  gemm_k<<<dim3(8, 1, 1), 256, 0, stream>>>(last_c + B_ * H_, W_init, nullptr, H_,
      b_init, nullptr, c, B_, H_, H_, H_, 0);
  gemm_k<<<dim3(8, 128, 1), 256, 0, stream>>>(enc, We, nullptr, H_,
      nullptr, nullptr, encp, S_ * B_, H_, H_, H_, 0);

  for (int t = 0; t < T_; t++) {
    const int N = (t == 0) ? B_ : N1_;
    const int ntiles = (t == 0) ? 1 : 2;         // 64-row tiles for gts gemm
    const int nt32 = (t == 0) ? 1 : 3;           // 32-row tiles for logits gemm
    const int bdiv = (t == 0) ? 1 : K_;
    const int lgrid = (t == 0) ? LG_MT : 480;    // XCD-grouped 1-D grid at t>0

    ppgemv_k<<<dim3(8, N), 256, 0, stream>>>(h, Wp, pp);
    score_k<<<dim3(8, N), 512, 0, stream>>>(pp, encp, Wv, mask, emb, tok, h,
        sc, xcat, bdiv, t == 0 ? 1 : 0);
    ctx_k<<<dim3(8, N), 256, 0, stream>>>(sc, enc, xcat, bdiv);
    gemm_k<<<dim3(32, ntiles, 4), 256, 0, stream>>>(xcat, W_ih, W_hh, E_ + H_,
        b_ih, b_hh, gts, N, 1280, 4 * H_, 320, GST);
    lstm_k<<<N, 256, 0, stream>>>(gts, c, xcat, h2, c2);
    lggemm_k<<<lgrid, 512, 0, stream>>>(xcat, Wc, bc, N,
        ptv, pti, pmx, psm, nt32);
    lgmerge_k<<<N, 256, 0, stream>>>(ptv, pti, pmx, psm, rtv, rti, rmax, rlse);
    if (t == 0) {
      reorder0_k<<<N1_, 256, 0, stream>>>(h2, c2, h, c, rtv, rti, rmax, rlse,
          cumA, eosA, tok, pA);
    } else {
      float* cumOld = (t & 1) ? cumA : cumB;
      float* cumNew = (t & 1) ? cumB : cumA;
      int* eosOld = (t & 1) ? eosA : eosB;
      int* eosNew = (t & 1) ? eosB : eosA;
      int* pOld   = (t & 1) ? pA : pB;
      int* pNew   = (t & 1) ? pB : pA;
      reorder1_k<<<N1_, 256, 0, stream>>>(h2, c2, h, c, rtv, rti, rmax, rlse,
          cumOld, cumNew, eosOld, eosNew, pOld, pNew, tok, t);
    }
  }

  // t=31 odd -> preds in pB, cum in cumB
  finalout_k<<<5, 256, 0, stream>>>(pB, cumB, (float*)d_out);
}